// Round 1
// baseline (446.621 us; speedup 1.0000x reference)
//
#include <hip/hip_runtime.h>
#include <hip/hip_bf16.h>
#include <cstdint>
#include <cstddef>

// Problem constants
#define SEQLEN 2048
#define NBATCH 2
#define NHEAD  16
#define HDIM   64
#define HID    1024
#define MROWS  (SEQLEN * NBATCH)  // 4096 rows, row r = s*NBATCH + b

typedef __bf16 bf16x8 __attribute__((ext_vector_type(8)));
typedef float f32x4 __attribute__((ext_vector_type(4)));
typedef unsigned short ushort8 __attribute__((ext_vector_type(8)));

static __device__ __forceinline__ unsigned short f2b(float f) {
    unsigned int u = __builtin_bit_cast(unsigned int, f);
    u = u + 0x7FFFu + ((u >> 16) & 1u);   // RNE (finite inputs only)
    return (unsigned short)(u >> 16);
}
static __device__ __forceinline__ float b2f(unsigned short s) {
    unsigned int u = ((unsigned int)s) << 16;
    return __builtin_bit_cast(float, u);
}

#define MFMA16(a, b, c) __builtin_amdgcn_mfma_f32_16x16x32_bf16((a), (b), (c), 0, 0, 0)

// ---------------------------------------------------------------------------
// Kernel A: QKV projection.  C = X @ W^T + bias, output bf16 to ws.
// z = 0(Q) / 1(K) / 2(V).  Q,K use hi/lo bf16 split (3 MFMAs) for precision.
// Tile 128x128, BK=32, 4 waves (2x2), each wave 64x64 (4x4 16x16 frags).
// ---------------------------------------------------------------------------
__global__ __launch_bounds__(256) void qkv_proj(
    const float* __restrict__ xq, const float* __restrict__ xk, const float* __restrict__ xv,
    const float* __restrict__ Wq, const float* __restrict__ Wk, const float* __restrict__ Wv,
    const float* __restrict__ bq, const float* __restrict__ bk, const float* __restrict__ bv,
    unsigned short* __restrict__ Qb, unsigned short* __restrict__ Kb, unsigned short* __restrict__ Vb)
{
    const int z = blockIdx.z;
    const float* X    = (z == 0) ? xq : (z == 1) ? xk : xv;
    const float* W    = (z == 0) ? Wq : (z == 1) ? Wk : Wv;
    const float* bias = (z == 0) ? bq : (z == 1) ? bk : bv;
    unsigned short* dst = (z == 0) ? Qb : (z == 1) ? Kb : Vb;
    const bool split = (z < 2);

    // stride 40 ushorts = 80B: 16B-aligned rows, ~2-way bank aliasing on b128
    __shared__ unsigned short Ah[128][40];
    __shared__ unsigned short Al[128][40];
    __shared__ unsigned short Bh[128][40];
    __shared__ unsigned short Bl[128][40];

    const int t = threadIdx.x;
    const int lane = t & 63, wid = t >> 6;
    const int wm = wid >> 1, wn = wid & 1;
    const int bm = blockIdx.x * 128, bn = blockIdx.y * 128;
    const int srow = t >> 1, scol = (t & 1) * 16;
    const int fr = lane & 15, fk = (lane >> 4) * 8;

    f32x4 acc[4][4] = {};

    for (int k0 = 0; k0 < HID; k0 += 32) {
        __syncthreads();
        // ---- stage A tile (fp32 -> bf16 hi/lo) ----
        {
            const float4* src = (const float4*)(X + (size_t)(bm + srow) * HID + k0 + scol);
            float4 f0 = src[0], f1 = src[1], f2 = src[2], f3 = src[3];
            float xs[16] = {f0.x, f0.y, f0.z, f0.w, f1.x, f1.y, f1.z, f1.w,
                            f2.x, f2.y, f2.z, f2.w, f3.x, f3.y, f3.z, f3.w};
            ushort8 h0, h1;
            #pragma unroll
            for (int j = 0; j < 8; ++j) { h0[j] = f2b(xs[j]); h1[j] = f2b(xs[j + 8]); }
            *(ushort8*)&Ah[srow][scol]     = h0;
            *(ushort8*)&Ah[srow][scol + 8] = h1;
            if (split) {
                ushort8 l0, l1;
                #pragma unroll
                for (int j = 0; j < 8; ++j) {
                    l0[j] = f2b(xs[j] - b2f(h0[j]));
                    l1[j] = f2b(xs[j + 8] - b2f(h1[j]));
                }
                *(ushort8*)&Al[srow][scol]     = l0;
                *(ushort8*)&Al[srow][scol + 8] = l1;
            }
        }
        // ---- stage B tile (W rows = output cols; W is [N][K] so B^T form) ----
        {
            const float4* src = (const float4*)(W + (size_t)(bn + srow) * HID + k0 + scol);
            float4 f0 = src[0], f1 = src[1], f2 = src[2], f3 = src[3];
            float xs[16] = {f0.x, f0.y, f0.z, f0.w, f1.x, f1.y, f1.z, f1.w,
                            f2.x, f2.y, f2.z, f2.w, f3.x, f3.y, f3.z, f3.w};
            ushort8 h0, h1;
            #pragma unroll
            for (int j = 0; j < 8; ++j) { h0[j] = f2b(xs[j]); h1[j] = f2b(xs[j + 8]); }
            *(ushort8*)&Bh[srow][scol]     = h0;
            *(ushort8*)&Bh[srow][scol + 8] = h1;
            if (split) {
                ushort8 l0, l1;
                #pragma unroll
                for (int j = 0; j < 8; ++j) {
                    l0[j] = f2b(xs[j] - b2f(h0[j]));
                    l1[j] = f2b(xs[j + 8] - b2f(h1[j]));
                }
                *(ushort8*)&Bl[srow][scol]     = l0;
                *(ushort8*)&Bl[srow][scol + 8] = l1;
            }
        }
        __syncthreads();

        bf16x8 a_h[4], b_h[4];
        #pragma unroll
        for (int m = 0; m < 4; ++m) a_h[m] = *(const bf16x8*)&Ah[wm * 64 + m * 16 + fr][fk];
        #pragma unroll
        for (int n = 0; n < 4; ++n) b_h[n] = *(const bf16x8*)&Bh[wn * 64 + n * 16 + fr][fk];

        if (split) {
            bf16x8 a_l[4], b_l[4];
            #pragma unroll
            for (int m = 0; m < 4; ++m) a_l[m] = *(const bf16x8*)&Al[wm * 64 + m * 16 + fr][fk];
            #pragma unroll
            for (int n = 0; n < 4; ++n) b_l[n] = *(const bf16x8*)&Bl[wn * 64 + n * 16 + fr][fk];
            #pragma unroll
            for (int m = 0; m < 4; ++m)
                #pragma unroll
                for (int n = 0; n < 4; ++n) {
                    acc[m][n] = MFMA16(a_h[m], b_h[n], acc[m][n]);
                    acc[m][n] = MFMA16(a_h[m], b_l[n], acc[m][n]);
                    acc[m][n] = MFMA16(a_l[m], b_h[n], acc[m][n]);
                }
        } else {
            #pragma unroll
            for (int m = 0; m < 4; ++m)
                #pragma unroll
                for (int n = 0; n < 4; ++n)
                    acc[m][n] = MFMA16(a_h[m], b_h[n], acc[m][n]);
        }
    }

    // epilogue: C/D layout col=lane&15, row=(lane>>4)*4+reg  [m89-verified]
    const int fg = lane >> 4;
    #pragma unroll
    for (int n = 0; n < 4; ++n) {
        const int gc = bn + wn * 64 + n * 16 + fr;
        const float bb = bias[gc];
        #pragma unroll
        for (int m = 0; m < 4; ++m) {
            #pragma unroll
            for (int r = 0; r < 4; ++r) {
                const int gr = bm + wm * 64 + m * 16 + fg * 4 + r;
                dst[(size_t)gr * HID + gc] = f2b(acc[m][n][r] + bb);
            }
        }
    }
}

// ---------------------------------------------------------------------------
// Kernel B: fused attention per (64 q-rows, head, batch).
// Pass 1: online row max/sum over K tiles.  Pass 2: recompute scores, write
// normalized attn (fp32, output 1), and accumulate P@V via LDS round-trip.
// ---------------------------------------------------------------------------
__global__ __launch_bounds__(256) void attn_fused(
    const unsigned short* __restrict__ Qb, const unsigned short* __restrict__ Kb,
    const unsigned short* __restrict__ Vb, float* __restrict__ attn_out,
    unsigned short* __restrict__ Hb)
{
    const int qblk = blockIdx.x;  // 0..31 (64 q rows each)
    const int h    = blockIdx.y;  // 0..15
    const int b    = blockIdx.z;  // 0..1

    __shared__ unsigned short Ks[128][72];    // K tile  [s'][d]
    __shared__ unsigned short Vt[64][136];    // V tile transposed [d][s']
    __shared__ unsigned short Pl[4][16][136]; // per-wave P tile [qrow][s']

    const int t = threadIdx.x, lane = t & 63, w = t >> 6;
    const int fr = lane & 15, fg = lane >> 4;
    const int srow = t >> 1, sc = (t & 1) * 32;

    // Q fragments (A operand): rows qblk*64 + w*16 + fr, K-dim = 64 (2 chunks)
    bf16x8 qf[2];
    {
        const int qrow = qblk * 64 + w * 16 + fr;
        const unsigned short* qp = Qb + ((size_t)qrow * NBATCH + b) * HID + h * HDIM;
        qf[0] = *(const bf16x8*)(qp + 0  + fg * 8);
        qf[1] = *(const bf16x8*)(qp + 32 + fg * 8);
    }

    float m_r[4] = {-3e38f, -3e38f, -3e38f, -3e38f};
    float l_r[4] = {0.f, 0.f, 0.f, 0.f};
    const float scale = 0.125f;  // 1/sqrt(64)

    // ---------------- pass 1: row max & sum ----------------
    for (int kt = 0; kt < 16; ++kt) {
        __syncthreads();
        {
            const ushort8* ksrc = (const ushort8*)(Kb + ((size_t)(kt * 128 + srow) * NBATCH + b) * HID + h * HDIM + sc);
            ushort8 u0 = ksrc[0], u1 = ksrc[1], u2 = ksrc[2], u3 = ksrc[3];
            *(ushort8*)&Ks[srow][sc + 0]  = u0;
            *(ushort8*)&Ks[srow][sc + 8]  = u1;
            *(ushort8*)&Ks[srow][sc + 16] = u2;
            *(ushort8*)&Ks[srow][sc + 24] = u3;
        }
        __syncthreads();

        f32x4 s_[8] = {};
        #pragma unroll
        for (int n = 0; n < 8; ++n) {
            #pragma unroll
            for (int kk = 0; kk < 2; ++kk) {
                bf16x8 kf = *(const bf16x8*)&Ks[n * 16 + fr][kk * 32 + fg * 8];
                s_[n] = MFMA16(qf[kk], kf, s_[n]);
            }
        }
        #pragma unroll
        for (int r = 0; r < 4; ++r) {
            float tm = -3e38f;
            #pragma unroll
            for (int n = 0; n < 8; ++n) tm = fmaxf(tm, s_[n][r]);
            tm *= scale;
            #pragma unroll
            for (int off = 1; off < 16; off <<= 1) tm = fmaxf(tm, __shfl_xor(tm, off));
            const float mnew = fmaxf(m_r[r], tm);
            float sum = 0.f;
            #pragma unroll
            for (int n = 0; n < 8; ++n) sum += __expf(s_[n][r] * scale - mnew);
            #pragma unroll
            for (int off = 1; off < 16; off <<= 1) sum += __shfl_xor(sum, off);
            l_r[r] = l_r[r] * __expf(m_r[r] - mnew) + sum;
            m_r[r] = mnew;
        }
    }

    float inv_r[4];
    #pragma unroll
    for (int r = 0; r < 4; ++r) inv_r[r] = 1.f / l_r[r];

    f32x4 oacc[4] = {};

    // ---------------- pass 2: attn write + PV ----------------
    for (int kt = 0; kt < 16; ++kt) {
        __syncthreads();
        {
            const ushort8* ksrc = (const ushort8*)(Kb + ((size_t)(kt * 128 + srow) * NBATCH + b) * HID + h * HDIM + sc);
            ushort8 u0 = ksrc[0], u1 = ksrc[1], u2 = ksrc[2], u3 = ksrc[3];
            *(ushort8*)&Ks[srow][sc + 0]  = u0;
            *(ushort8*)&Ks[srow][sc + 8]  = u1;
            *(ushort8*)&Ks[srow][sc + 16] = u2;
            *(ushort8*)&Ks[srow][sc + 24] = u3;
        }
        {
            const ushort8* vsrc = (const ushort8*)(Vb + ((size_t)(kt * 128 + srow) * NBATCH + b) * HID + h * HDIM + sc);
            ushort8 u0 = vsrc[0], u1 = vsrc[1], u2 = vsrc[2], u3 = vsrc[3];
            #pragma unroll
            for (int j = 0; j < 8; ++j) {
                Vt[sc + j][srow]      = u0[j];
                Vt[sc + 8 + j][srow]  = u1[j];
                Vt[sc + 16 + j][srow] = u2[j];
                Vt[sc + 24 + j][srow] = u3[j];
            }
        }
        __syncthreads();

        f32x4 s_[8] = {};
        #pragma unroll
        for (int n = 0; n < 8; ++n) {
            #pragma unroll
            for (int kk = 0; kk < 2; ++kk) {
                bf16x8 kf = *(const bf16x8*)&Ks[n * 16 + fr][kk * 32 + fg * 8];
                s_[n] = MFMA16(qf[kk], kf, s_[n]);
            }
        }

        float* abase = attn_out + (((size_t)(b * NHEAD + h) * SEQLEN) + qblk * 64 + w * 16 + fg * 4) * SEQLEN + kt * 128;
        #pragma unroll
        for (int n = 0; n < 8; ++n) {
            #pragma unroll
            for (int r = 0; r < 4; ++r) {
                const float p = __expf(s_[n][r] * scale - m_r[r]) * inv_r[r];
                abase[(size_t)r * SEQLEN + n * 16 + fr] = p;
                Pl[w][fg * 4 + r][n * 16 + fr] = f2b(p);
            }
        }
        __syncthreads();

        // PV: D(16x64) += P(16x128) @ V(128x64); B-frag from transposed Vt
        #pragma unroll
        for (int kk = 0; kk < 4; ++kk) {
            bf16x8 pa = *(const bf16x8*)&Pl[w][fr][kk * 32 + fg * 8];
            #pragma unroll
            for (int n = 0; n < 4; ++n) {
                bf16x8 vf = *(const bf16x8*)&Vt[n * 16 + fr][kk * 32 + fg * 8];
                oacc[n] = MFMA16(pa, vf, oacc[n]);
            }
        }
    }

    // epilogue: head output -> Hb bf16, layout [r = q*2+b][h*64+d]
    #pragma unroll
    for (int n = 0; n < 4; ++n) {
        const int d = n * 16 + fr;
        #pragma unroll
        for (int r = 0; r < 4; ++r) {
            const int qr = qblk * 64 + w * 16 + fg * 4 + r;
            Hb[((size_t)qr * NBATCH + b) * HID + h * HDIM + d] = f2b(oacc[n][r]);
        }
    }
}

// ---------------------------------------------------------------------------
// Kernel C: output projection.  out = H @ Wo^T + bo (fp32 out).
// ---------------------------------------------------------------------------
__global__ __launch_bounds__(256) void out_proj(
    const unsigned short* __restrict__ Hb, const float* __restrict__ Wo,
    const float* __restrict__ bo, float* __restrict__ out)
{
    __shared__ unsigned short Ah[128][40];
    __shared__ unsigned short Bh[128][40];

    const int t = threadIdx.x;
    const int lane = t & 63, wid = t >> 6;
    const int wm = wid >> 1, wn = wid & 1;
    const int bm = blockIdx.x * 128, bn = blockIdx.y * 128;
    const int srow = t >> 1, scol = (t & 1) * 16;
    const int fr = lane & 15, fk = (lane >> 4) * 8;

    f32x4 acc[4][4] = {};

    for (int k0 = 0; k0 < HID; k0 += 32) {
        __syncthreads();
        {
            const ushort8* src = (const ushort8*)(Hb + (size_t)(bm + srow) * HID + k0 + scol);
            *(ushort8*)&Ah[srow][scol]     = src[0];
            *(ushort8*)&Ah[srow][scol + 8] = src[1];
        }
        {
            const float4* src = (const float4*)(Wo + (size_t)(bn + srow) * HID + k0 + scol);
            float4 f0 = src[0], f1 = src[1], f2 = src[2], f3 = src[3];
            float xs[16] = {f0.x, f0.y, f0.z, f0.w, f1.x, f1.y, f1.z, f1.w,
                            f2.x, f2.y, f2.z, f2.w, f3.x, f3.y, f3.z, f3.w};
            ushort8 h0, h1;
            #pragma unroll
            for (int j = 0; j < 8; ++j) { h0[j] = f2b(xs[j]); h1[j] = f2b(xs[j + 8]); }
            *(ushort8*)&Bh[srow][scol]     = h0;
            *(ushort8*)&Bh[srow][scol + 8] = h1;
        }
        __syncthreads();

        bf16x8 a_h[4], b_h[4];
        #pragma unroll
        for (int m = 0; m < 4; ++m) a_h[m] = *(const bf16x8*)&Ah[wm * 64 + m * 16 + fr][fk];
        #pragma unroll
        for (int n = 0; n < 4; ++n) b_h[n] = *(const bf16x8*)&Bh[wn * 64 + n * 16 + fr][fk];
        #pragma unroll
        for (int m = 0; m < 4; ++m)
            #pragma unroll
            for (int n = 0; n < 4; ++n)
                acc[m][n] = MFMA16(a_h[m], b_h[n], acc[m][n]);
    }

    const int fg = lane >> 4;
    #pragma unroll
    for (int n = 0; n < 4; ++n) {
        const int gc = bn + wn * 64 + n * 16 + fr;
        const float bb = bo[gc];
        #pragma unroll
        for (int m = 0; m < 4; ++m) {
            #pragma unroll
            for (int r = 0; r < 4; ++r) {
                const int gr = bm + wm * 64 + m * 16 + fg * 4 + r;
                out[(size_t)gr * HID + gc] = acc[m][n][r] + bb;
            }
        }
    }
}

// ---------------------------------------------------------------------------
extern "C" void kernel_launch(void* const* d_in, const int* in_sizes, int n_in,
                              void* d_out, int out_size, void* d_ws, size_t ws_size,
                              hipStream_t stream)
{
    (void)in_sizes; (void)n_in; (void)out_size;

    const float* query = (const float*)d_in[0];
    const float* key   = (const float*)d_in[1];
    const float* value = (const float*)d_in[2];
    const float* Wq    = (const float*)d_in[3];
    const float* bq    = (const float*)d_in[4];
    const float* Wk    = (const float*)d_in[5];
    const float* bk    = (const float*)d_in[6];
    const float* Wv    = (const float*)d_in[7];
    const float* bv    = (const float*)d_in[8];
    const float* Wo    = (const float*)d_in[9];
    const float* bo    = (const float*)d_in[10];

    float* out0 = (float*)d_out;                          // (S,B,HID) fp32
    float* attn = out0 + (size_t)MROWS * HID;             // (B,H,S,S) fp32

    const size_t nbuf = (size_t)MROWS * HID;              // bf16 elems per buffer
    if (ws_size < nbuf * 2 * 4) return;                   // need 32 MB scratch
    unsigned short* Qb = (unsigned short*)d_ws;
    unsigned short* Kb = Qb + nbuf;
    unsigned short* Vb = Kb + nbuf;
    unsigned short* Hb = Vb + nbuf;

    qkv_proj<<<dim3(32, 8, 3), 256, 0, stream>>>(query, key, value, Wq, Wk, Wv,
                                                 bq, bk, bv, Qb, Kb, Vb);
    attn_fused<<<dim3(32, NHEAD, NBATCH), 256, 0, stream>>>(Qb, Kb, Vb, attn, Hb);
    out_proj<<<dim3(32, 8), 256, 0, stream>>>(Hb, Wo, bo, out0);
}

// Round 2
// 374.613 us; speedup vs baseline: 1.1922x; 1.1922x over previous
//
#include <hip/hip_runtime.h>
#include <hip/hip_bf16.h>
#include <cstdint>
#include <cstddef>

#define SEQLEN 2048
#define NBATCH 2
#define NHEAD  16
#define HDIM   64
#define HID    1024
#define MROWS  4096   // row r = s*2 + b

typedef __bf16 bf16x8 __attribute__((ext_vector_type(8)));
typedef float f32x4 __attribute__((ext_vector_type(4)));
typedef unsigned short ushort8 __attribute__((ext_vector_type(8)));

#define MFMA16(a, b, c) __builtin_amdgcn_mfma_f32_16x16x32_bf16((a), (b), (c), 0, 0, 0)

#define GLOAD_LDS16(g, l)                                                        \
    __builtin_amdgcn_global_load_lds(                                            \
        (const __attribute__((address_space(1))) void*)(g),                      \
        (__attribute__((address_space(3))) void*)(l), 16, 0, 0)

// ---------------------------------------------------------------------------
// Kernel A: QKV projection. C = X @ W^T + bias -> bf16. Tile 128x128, BK=32.
// ---------------------------------------------------------------------------
__global__ __launch_bounds__(256) void qkv_proj(
    const float* __restrict__ xq, const float* __restrict__ xk, const float* __restrict__ xv,
    const float* __restrict__ Wq, const float* __restrict__ Wk, const float* __restrict__ Wv,
    const float* __restrict__ bq, const float* __restrict__ bk, const float* __restrict__ bv,
    unsigned short* __restrict__ Qb, unsigned short* __restrict__ Kb, unsigned short* __restrict__ Vb)
{
    const int z = blockIdx.z;
    const float* X    = (z == 0) ? xq : (z == 1) ? xk : xv;
    const float* W    = (z == 0) ? Wq : (z == 1) ? Wk : Wv;
    const float* bias = (z == 0) ? bq : (z == 1) ? bk : bv;
    unsigned short* dst = (z == 0) ? Qb : (z == 1) ? Kb : Vb;

    __shared__ unsigned short Ah[128][40];   // stride 80B: ~2-way aliasing (free)
    __shared__ unsigned short Bh[128][40];

    const int t = threadIdx.x;
    const int lane = t & 63, wid = t >> 6;
    const int wm = wid >> 1, wn = wid & 1;
    const int bm = blockIdx.x * 128, bn = blockIdx.y * 128;
    const int srow = t >> 1, scol = (t & 1) * 16;
    const int fr = lane & 15, fk = (lane >> 4) * 8;

    f32x4 acc[4][4] = {};

    for (int k0 = 0; k0 < HID; k0 += 32) {
        __syncthreads();
        {
            const float4* src = (const float4*)(X + (size_t)(bm + srow) * HID + k0 + scol);
            float4 f0 = src[0], f1 = src[1], f2 = src[2], f3 = src[3];
            float xs[16] = {f0.x, f0.y, f0.z, f0.w, f1.x, f1.y, f1.z, f1.w,
                            f2.x, f2.y, f2.z, f2.w, f3.x, f3.y, f3.z, f3.w};
            bf16x8 h0, h1;
            #pragma unroll
            for (int j = 0; j < 8; ++j) { h0[j] = (__bf16)xs[j]; h1[j] = (__bf16)xs[j + 8]; }
            *(bf16x8*)&Ah[srow][scol]     = h0;
            *(bf16x8*)&Ah[srow][scol + 8] = h1;
        }
        {
            const float4* src = (const float4*)(W + (size_t)(bn + srow) * HID + k0 + scol);
            float4 f0 = src[0], f1 = src[1], f2 = src[2], f3 = src[3];
            float xs[16] = {f0.x, f0.y, f0.z, f0.w, f1.x, f1.y, f1.z, f1.w,
                            f2.x, f2.y, f2.z, f2.w, f3.x, f3.y, f3.z, f3.w};
            bf16x8 h0, h1;
            #pragma unroll
            for (int j = 0; j < 8; ++j) { h0[j] = (__bf16)xs[j]; h1[j] = (__bf16)xs[j + 8]; }
            *(bf16x8*)&Bh[srow][scol]     = h0;
            *(bf16x8*)&Bh[srow][scol + 8] = h1;
        }
        __syncthreads();

        bf16x8 a_h[4], b_h[4];
        #pragma unroll
        for (int m = 0; m < 4; ++m) a_h[m] = *(const bf16x8*)&Ah[wm * 64 + m * 16 + fr][fk];
        #pragma unroll
        for (int n = 0; n < 4; ++n) b_h[n] = *(const bf16x8*)&Bh[wn * 64 + n * 16 + fr][fk];
        #pragma unroll
        for (int m = 0; m < 4; ++m)
            #pragma unroll
            for (int n = 0; n < 4; ++n)
                acc[m][n] = MFMA16(a_h[m], b_h[n], acc[m][n]);
    }

    const int fg = lane >> 4;
    #pragma unroll
    for (int n = 0; n < 4; ++n) {
        const int gc = bn + wn * 64 + n * 16 + fr;
        const float bb = bias[gc];
        #pragma unroll
        for (int m = 0; m < 4; ++m)
            #pragma unroll
            for (int r = 0; r < 4; ++r) {
                const int gr = bm + wm * 64 + m * 16 + fg * 4 + r;
                *(__bf16*)&dst[(size_t)gr * HID + gc] = (__bf16)(acc[m][n][r] + bb);
            }
    }
}

// ---------------------------------------------------------------------------
// Kernel A2: transpose V -> Vt [b][h][d][s]
// ---------------------------------------------------------------------------
__global__ __launch_bounds__(256) void vtrans(
    const unsigned short* __restrict__ Vb, unsigned short* __restrict__ Vt)
{
    const int t = threadIdx.x;
    const int s = blockIdx.x * 256 + t;
    const int h = blockIdx.y, b = blockIdx.z;

    const unsigned short* src = Vb + ((size_t)s * 2 + b) * HID + h * HDIM;
    ushort8 v[8];
    #pragma unroll
    for (int i = 0; i < 8; ++i) v[i] = *(const ushort8*)(src + i * 8);

    unsigned short* dst = Vt + (((size_t)(b * NHEAD + h)) << 17) + s;  // *64*2048
    #pragma unroll
    for (int i = 0; i < 8; ++i)
        #pragma unroll
        for (int j = 0; j < 8; ++j)
            dst[(size_t)(i * 8 + j) * SEQLEN] = v[i][j];
}

// ---------------------------------------------------------------------------
// Kernel B: fused attention. 128 q-rows/block (4 waves x 32), two passes.
// Pass 1: row sums of exp(s/8) (no max subtraction; clamp for safety).
// Pass 2: recompute, write normalized attn fp32 (coalesced via LDS), PV MFMA.
// K staged via global_load_lds with XOR-swizzled source; V read from Vt.
// ---------------------------------------------------------------------------
__global__ __launch_bounds__(256) void attn2(
    const unsigned short* __restrict__ Qb, const unsigned short* __restrict__ Kb,
    const unsigned short* __restrict__ Vt, float* __restrict__ attn_out,
    unsigned short* __restrict__ Hb)
{
    __shared__ unsigned short Ks[128 * 64];      // 16 KB, XOR-swizzled rows of 128B
    __shared__ unsigned short Pl[4 * 32 * 128];  // 32 KB, per-wave 32x128 bf16

    // XCD-chunked swizzle: 64 consecutive logical blocks (4 (h,b) groups) per XCD
    const int flat = blockIdx.x + (blockIdx.y << 4) + (blockIdx.z << 8);
    const int nf = (flat & 7) * 64 + (flat >> 3);
    const int qblk = nf & 15, h = (nf >> 4) & 15, b = nf >> 8;

    const int t = threadIdx.x, lane = t & 63, w = t >> 6;
    const int fr = lane & 15, fg = lane >> 4;
    const int fg4 = fg << 2, fg16 = fg << 4;
    const int qbase = qblk * 128 + w * 32;
    const float scale = 0.125f;

    bf16x8 qf[2][2];
    #pragma unroll
    for (int mi = 0; mi < 2; ++mi) {
        const int q = qbase + mi * 16 + fr;
        const unsigned short* qp = Qb + (((size_t)q * 2 + b) << 10) + (h << 6);
        qf[mi][0] = *(const bf16x8*)(qp + (fg << 3));
        qf[mi][1] = *(const bf16x8*)(qp + 32 + (fg << 3));
    }

    const char* Ksc = (const char*)Ks;
    char* Plc = (char*)&Pl[w * 4096];

    float lsum[2][4] = {};

    // ---------------- pass 1 ----------------
    for (int kt = 0; kt < 16; ++kt) {
        __syncthreads();
        #pragma unroll
        for (int c = 0; c < 4; ++c) {
            const int row_l = (w << 5) + (c << 3) + (lane >> 3);
            const int sp = (kt << 7) + row_l;
            const unsigned short* src = Kb + (((size_t)sp * 2 + b) << 10) + (h << 6)
                                         + (((lane & 7) ^ (row_l & 7)) << 3);
            GLOAD_LDS16(src, &Ks[((w << 5) + (c << 3)) * 64]);
        }
        __syncthreads();

        f32x4 s_[2][8] = {};
        #pragma unroll
        for (int n = 0; n < 8; ++n) {
            const int row = (n << 4) + fr;
            const int rx = (row & 7) << 4;
            #pragma unroll
            for (int kk = 0; kk < 2; ++kk) {
                bf16x8 kf = *(const bf16x8*)(Ksc + (row << 7) + (((kk << 6) | fg16) ^ rx));
                s_[0][n] = MFMA16(qf[0][kk], kf, s_[0][n]);
                s_[1][n] = MFMA16(qf[1][kk], kf, s_[1][n]);
            }
        }
        #pragma unroll
        for (int mi = 0; mi < 2; ++mi)
            #pragma unroll
            for (int r = 0; r < 4; ++r) {
                float a = 0.f;
                #pragma unroll
                for (int n = 0; n < 8; ++n)
                    a += __expf(fminf(s_[mi][n][r] * scale, 60.f));
                lsum[mi][r] += a;
            }
    }

    float inv[2][4];
    #pragma unroll
    for (int mi = 0; mi < 2; ++mi)
        #pragma unroll
        for (int r = 0; r < 4; ++r) {
            float v = lsum[mi][r];
            v += __shfl_xor(v, 1); v += __shfl_xor(v, 2);
            v += __shfl_xor(v, 4); v += __shfl_xor(v, 8);
            inv[mi][r] = 1.f / v;
        }

    f32x4 oacc[2][4] = {};
    float* attnB = attn_out + ((size_t)((b << 4) + h) << 22);   // *2048*2048
    const size_t vhead = (size_t)((b << 4) + h) << 6;           // *64

    // ---------------- pass 2 ----------------
    for (int kt = 0; kt < 16; ++kt) {
        __syncthreads();
        #pragma unroll
        for (int c = 0; c < 4; ++c) {
            const int row_l = (w << 5) + (c << 3) + (lane >> 3);
            const int sp = (kt << 7) + row_l;
            const unsigned short* src = Kb + (((size_t)sp * 2 + b) << 10) + (h << 6)
                                         + (((lane & 7) ^ (row_l & 7)) << 3);
            GLOAD_LDS16(src, &Ks[((w << 5) + (c << 3)) * 64]);
        }
        __syncthreads();

        f32x4 s_[2][8] = {};
        #pragma unroll
        for (int n = 0; n < 8; ++n) {
            const int row = (n << 4) + fr;
            const int rx = (row & 7) << 4;
            #pragma unroll
            for (int kk = 0; kk < 2; ++kk) {
                bf16x8 kf = *(const bf16x8*)(Ksc + (row << 7) + (((kk << 6) | fg16) ^ rx));
                s_[0][n] = MFMA16(qf[0][kk], kf, s_[0][n]);
                s_[1][n] = MFMA16(qf[1][kk], kf, s_[1][n]);
            }
        }

        // normalized P -> Pl (bf16, swizzled)
        #pragma unroll
        for (int mi = 0; mi < 2; ++mi)
            #pragma unroll
            for (int n = 0; n < 8; ++n) {
                const int colb = (n << 5) | (fr << 1);
                #pragma unroll
                for (int r = 0; r < 4; ++r) {
                    const int row = (mi << 4) + fg4 + r;
                    const float p = __expf(fminf(s_[mi][n][r] * scale, 60.f)) * inv[mi][r];
                    *(__bf16*)(Plc + (row << 8) + (colb ^ ((row & 7) << 4))) = (__bf16)p;
                }
            }
        asm volatile("s_waitcnt lgkmcnt(0)" ::: "memory");
        __builtin_amdgcn_sched_barrier(0);

        // attn write: 512B-contiguous float2 stores per row
        {
            float* ab = attnB + (size_t)qbase * SEQLEN + (kt << 7) + (lane << 1);
            #pragma unroll
            for (int j = 0; j < 32; ++j) {
                const unsigned int u =
                    *(const unsigned int*)(Plc + (j << 8) + ((lane << 2) ^ ((j & 7) << 4)));
                float2 f;
                f.x = __builtin_bit_cast(float, u << 16);
                f.y = __builtin_bit_cast(float, u & 0xFFFF0000u);
                *(float2*)(ab + (size_t)j * SEQLEN) = f;
            }
        }

        // PV: oacc += P(32x128) @ V(128x64), B-frags direct from Vt (global)
        #pragma unroll
        for (int kk2 = 0; kk2 < 4; ++kk2) {
            const int cb = ((kk2 << 6) | fg16) ^ ((fr & 7) << 4);
            bf16x8 pa0 = *(const bf16x8*)(Plc + (fr << 8) + cb);
            bf16x8 pa1 = *(const bf16x8*)(Plc + ((16 + fr) << 8) + cb);
            #pragma unroll
            for (int n2 = 0; n2 < 4; ++n2) {
                bf16x8 vf = *(const bf16x8*)(Vt + ((vhead + (n2 << 4) + fr) << 11)
                                             + (kt << 7) + (kk2 << 5) + (fg << 3));
                oacc[0][n2] = MFMA16(pa0, vf, oacc[0][n2]);
                oacc[1][n2] = MFMA16(pa1, vf, oacc[1][n2]);
            }
        }
    }

    #pragma unroll
    for (int mi = 0; mi < 2; ++mi)
        #pragma unroll
        for (int n2 = 0; n2 < 4; ++n2)
            #pragma unroll
            for (int r = 0; r < 4; ++r) {
                const int q = qbase + (mi << 4) + fg4 + r;
                *(__bf16*)&Hb[(((size_t)q * 2 + b) << 10) + (h << 6) + (n2 << 4) + fr] =
                    (__bf16)oacc[mi][n2][r];
            }
}

// ---------------------------------------------------------------------------
// Kernel C: out = H @ Wo^T + bo (fp32). A staged via global_load_lds (m97).
// ---------------------------------------------------------------------------
__global__ __launch_bounds__(256) void out_proj(
    const unsigned short* __restrict__ Hb, const float* __restrict__ Wo,
    const float* __restrict__ bo, float* __restrict__ out)
{
    __shared__ unsigned short Ah[128 * 32];  // linear, 64B rows (m97 pattern)
    __shared__ unsigned short Bh[128][40];

    const int t = threadIdx.x;
    const int lane = t & 63, wid = t >> 6;
    const int wm = wid >> 1, wn = wid & 1;
    const int bm = blockIdx.x * 128, bn = blockIdx.y * 128;
    const int srow = t >> 1, scol = (t & 1) * 16;
    const int fr = lane & 15, fg = lane >> 4, fk = fg * 8;

    f32x4 acc[4][4] = {};

    for (int k0 = 0; k0 < HID; k0 += 32) {
        __syncthreads();
        #pragma unroll
        for (int c = 0; c < 2; ++c) {
            const int row_l = wid * 32 + c * 16 + (lane >> 2);
            const unsigned short* src = Hb + (size_t)(bm + row_l) * HID + k0 + ((lane & 3) << 3);
            GLOAD_LDS16(src, &Ah[(wid * 32 + c * 16) * 32]);
        }
        {
            const float4* src = (const float4*)(Wo + (size_t)(bn + srow) * HID + k0 + scol);
            float4 f0 = src[0], f1 = src[1], f2 = src[2], f3 = src[3];
            float xs[16] = {f0.x, f0.y, f0.z, f0.w, f1.x, f1.y, f1.z, f1.w,
                            f2.x, f2.y, f2.z, f2.w, f3.x, f3.y, f3.z, f3.w};
            bf16x8 h0, h1;
            #pragma unroll
            for (int j = 0; j < 8; ++j) { h0[j] = (__bf16)xs[j]; h1[j] = (__bf16)xs[j + 8]; }
            *(bf16x8*)&Bh[srow][scol]     = h0;
            *(bf16x8*)&Bh[srow][scol + 8] = h1;
        }
        __syncthreads();

        bf16x8 a_h[4], b_h[4];
        #pragma unroll
        for (int m = 0; m < 4; ++m)
            a_h[m] = *(const bf16x8*)&Ah[(wm * 64 + m * 16 + fr) * 32 + fk];
        #pragma unroll
        for (int n = 0; n < 4; ++n) b_h[n] = *(const bf16x8*)&Bh[wn * 64 + n * 16 + fr][fk];
        #pragma unroll
        for (int m = 0; m < 4; ++m)
            #pragma unroll
            for (int n = 0; n < 4; ++n)
                acc[m][n] = MFMA16(a_h[m], b_h[n], acc[m][n]);
    }

    const int fg2 = lane >> 4;
    #pragma unroll
    for (int n = 0; n < 4; ++n) {
        const int gc = bn + wn * 64 + n * 16 + fr;
        const float bb = bo[gc];
        #pragma unroll
        for (int m = 0; m < 4; ++m)
            #pragma unroll
            for (int r = 0; r < 4; ++r) {
                const int gr = bm + wm * 64 + m * 16 + fg2 * 4 + r;
                out[(size_t)gr * HID + gc] = acc[m][n][r] + bb;
            }
    }
}

// ---------------------------------------------------------------------------
extern "C" void kernel_launch(void* const* d_in, const int* in_sizes, int n_in,
                              void* d_out, int out_size, void* d_ws, size_t ws_size,
                              hipStream_t stream)
{
    (void)in_sizes; (void)n_in; (void)out_size;

    const float* query = (const float*)d_in[0];
    const float* key   = (const float*)d_in[1];
    const float* value = (const float*)d_in[2];
    const float* Wq    = (const float*)d_in[3];
    const float* bq    = (const float*)d_in[4];
    const float* Wk    = (const float*)d_in[5];
    const float* bk    = (const float*)d_in[6];
    const float* Wv    = (const float*)d_in[7];
    const float* bv    = (const float*)d_in[8];
    const float* Wo    = (const float*)d_in[9];
    const float* bo    = (const float*)d_in[10];

    float* out0 = (float*)d_out;
    float* attn = out0 + (size_t)MROWS * HID;

    if (ws_size < (size_t)32 * 1024 * 1024) return;
    const size_t nbuf = (size_t)MROWS * HID;            // 4M bf16 = 8MB
    unsigned short* Qb = (unsigned short*)d_ws;         // [0, 8MB)
    unsigned short* Kb = Qb + nbuf;                     // [8, 16MB)
    unsigned short* Vb = Kb + nbuf;                     // [16, 24MB)  (reused as Hb)
    unsigned short* Vt = Vb + nbuf;                     // [24, 32MB)
    unsigned short* Hb = Vb;                            // Vb dead after vtrans

    qkv_proj<<<dim3(32, 8, 3), 256, 0, stream>>>(query, key, value, Wq, Wk, Wv,
                                                 bq, bk, bv, Qb, Kb, Vb);
    vtrans<<<dim3(8, NHEAD, NBATCH), 256, 0, stream>>>(Vb, Vt);
    attn2<<<dim3(16, NHEAD, NBATCH), 256, 0, stream>>>(Qb, Kb, Vt, attn, Hb);
    out_proj<<<dim3(32, 8), 256, 0, stream>>>(Hb, Wo, bo, out0);
}

// Round 3
// 326.639 us; speedup vs baseline: 1.3673x; 1.1469x over previous
//
#include <hip/hip_runtime.h>
#include <hip/hip_bf16.h>
#include <cstdint>
#include <cstddef>

#define SEQLEN 2048
#define NBATCH 2
#define NHEAD  16
#define HDIM   64
#define HID    1024
#define MROWS  4096   // row r = s*2 + b

typedef __bf16 bf16x8 __attribute__((ext_vector_type(8)));
typedef float f32x4 __attribute__((ext_vector_type(4)));
typedef unsigned short ushort8 __attribute__((ext_vector_type(8)));

#define MFMA16(a, b, c) __builtin_amdgcn_mfma_f32_16x16x32_bf16((a), (b), (c), 0, 0, 0)

#define GLOAD_LDS16(g, l)                                                        \
    __builtin_amdgcn_global_load_lds(                                            \
        (const __attribute__((address_space(1))) void*)(g),                      \
        (__attribute__((address_space(3))) void*)(l), 16, 0, 0)

static __device__ __forceinline__ unsigned int pack_bf16_pair(float lo, float hi) {
    unsigned short a = __builtin_bit_cast(unsigned short, (__bf16)lo);
    unsigned short b = __builtin_bit_cast(unsigned short, (__bf16)hi);
    return ((unsigned int)b << 16) | a;
}

// ---------------------------------------------------------------------------
// conv6: fp32 -> bf16 for {query,key,value,Wq,Wk,Wv} into scratch (attn area)
// ---------------------------------------------------------------------------
__global__ __launch_bounds__(256) void conv6(
    const float* __restrict__ s0, const float* __restrict__ s1, const float* __restrict__ s2,
    const float* __restrict__ s3, const float* __restrict__ s4, const float* __restrict__ s5,
    unsigned short* __restrict__ Sc)
{
    const int y = blockIdx.y;
    const float* src = (y == 0) ? s0 : (y == 1) ? s1 : (y == 2) ? s2
                     : (y == 3) ? s3 : (y == 4) ? s4 : s5;
    const size_t M1 = 1u << 20;
    unsigned short* dst = (y < 3) ? (Sc + (size_t)y * 4 * M1) : (Sc + 12 * M1 + (size_t)(y - 3) * M1);
    const size_t n = (y < 3) ? 4 * M1 : M1;

    const size_t i = ((size_t)blockIdx.x * 256 + threadIdx.x) * 8;
    if (i >= n) return;
    float4 f0 = *(const float4*)(src + i);
    float4 f1 = *(const float4*)(src + i + 4);
    ushort8 o;
    o[0] = __builtin_bit_cast(unsigned short, (__bf16)f0.x);
    o[1] = __builtin_bit_cast(unsigned short, (__bf16)f0.y);
    o[2] = __builtin_bit_cast(unsigned short, (__bf16)f0.z);
    o[3] = __builtin_bit_cast(unsigned short, (__bf16)f0.w);
    o[4] = __builtin_bit_cast(unsigned short, (__bf16)f1.x);
    o[5] = __builtin_bit_cast(unsigned short, (__bf16)f1.y);
    o[6] = __builtin_bit_cast(unsigned short, (__bf16)f1.z);
    o[7] = __builtin_bit_cast(unsigned short, (__bf16)f1.w);
    *(ushort8*)(dst + i) = o;
}

__global__ __launch_bounds__(256) void wconv(
    const float* __restrict__ Wo, unsigned short* __restrict__ Wob)
{
    const size_t i = ((size_t)blockIdx.x * 256 + threadIdx.x) * 8;
    float4 f0 = *(const float4*)(Wo + i);
    float4 f1 = *(const float4*)(Wo + i + 4);
    ushort8 o;
    o[0] = __builtin_bit_cast(unsigned short, (__bf16)f0.x);
    o[1] = __builtin_bit_cast(unsigned short, (__bf16)f0.y);
    o[2] = __builtin_bit_cast(unsigned short, (__bf16)f0.z);
    o[3] = __builtin_bit_cast(unsigned short, (__bf16)f0.w);
    o[4] = __builtin_bit_cast(unsigned short, (__bf16)f1.x);
    o[5] = __builtin_bit_cast(unsigned short, (__bf16)f1.y);
    o[6] = __builtin_bit_cast(unsigned short, (__bf16)f1.z);
    o[7] = __builtin_bit_cast(unsigned short, (__bf16)f1.w);
    *(ushort8*)(Wob + i) = o;
}

// ---------------------------------------------------------------------------
// bf16 GEMM tile body (m97-style): C[128x128] = A[128xK] @ B[128xK]^T (+bias)
// Both tiles staged via global_load_lds w16, XOR-swizzled. BK=64.
// ---------------------------------------------------------------------------
#define GEMM_STAGE(LDSBUF, SRCP)                                                  \
    _Pragma("unroll")                                                             \
    for (int c = 0; c < 4; ++c) {                                                 \
        const int rb = (w << 5) + (c << 3);                                       \
        const int row = rb + (lane >> 3);                                         \
        const unsigned short* src = (SRCP) + (size_t)row * HID + k0               \
                                  + (((lane & 7) ^ ((lane >> 3) & 7)) << 3);      \
        GLOAD_LDS16(src, &LDSBUF[rb * 64]);                                       \
    }

__global__ __launch_bounds__(256) void qkv_gemm(
    const unsigned short* __restrict__ Sc,
    const float* __restrict__ bq, const float* __restrict__ bk, const float* __restrict__ bv,
    unsigned short* __restrict__ Qb, unsigned short* __restrict__ Kb, unsigned short* __restrict__ Vb)
{
    const int z = blockIdx.z;
    const size_t M1 = 1u << 20;
    const unsigned short* A = Sc + (size_t)z * 4 * M1;
    const unsigned short* B = Sc + 12 * M1 + (size_t)z * M1;
    const float* bias = (z == 0) ? bq : (z == 1) ? bk : bv;
    unsigned short* dst = (z == 0) ? Qb : (z == 1) ? Kb : Vb;

    __shared__ unsigned short As[128 * 64];
    __shared__ unsigned short Bs[128 * 64];

    const int t = threadIdx.x, lane = t & 63, w = t >> 6;
    const int wm = w >> 1, wn = w & 1;
    const int bm = blockIdx.x * 128, bn = blockIdx.y * 128;
    const int fr = lane & 15, fg = lane >> 4;

    f32x4 acc[4][4] = {};
    const char* Ac = (const char*)As;
    const char* Bc = (const char*)Bs;

    for (int k0 = 0; k0 < HID; k0 += 64) {
        __syncthreads();
        GEMM_STAGE(As, A + (size_t)bm * HID)
        GEMM_STAGE(Bs, B + (size_t)bn * HID)
        __syncthreads();

        #pragma unroll
        for (int kk = 0; kk < 2; ++kk) {
            bf16x8 a_h[4], b_h[4];
            #pragma unroll
            for (int m = 0; m < 4; ++m) {
                const int row = wm * 64 + m * 16 + fr;
                a_h[m] = *(const bf16x8*)(Ac + (row << 7) + (((kk << 6) | (fg << 4)) ^ ((row & 7) << 4)));
            }
            #pragma unroll
            for (int n = 0; n < 4; ++n) {
                const int row = wn * 64 + n * 16 + fr;
                b_h[n] = *(const bf16x8*)(Bc + (row << 7) + (((kk << 6) | (fg << 4)) ^ ((row & 7) << 4)));
            }
            __builtin_amdgcn_s_setprio(1);
            #pragma unroll
            for (int m = 0; m < 4; ++m)
                #pragma unroll
                for (int n = 0; n < 4; ++n)
                    acc[m][n] = MFMA16(a_h[m], b_h[n], acc[m][n]);
            __builtin_amdgcn_s_setprio(0);
        }
    }

    #pragma unroll
    for (int n = 0; n < 4; ++n) {
        const int gc = bn + wn * 64 + n * 16 + fr;
        const float bb = bias[gc];
        #pragma unroll
        for (int m = 0; m < 4; ++m)
            #pragma unroll
            for (int r = 0; r < 4; ++r) {
                const int gr = bm + wm * 64 + m * 16 + fg * 4 + r;
                *(__bf16*)&dst[(size_t)gr * HID + gc] = (__bf16)(acc[m][n][r] + bb);
            }
    }
}

// ---------------------------------------------------------------------------
// vtrans: LDS-tiled transpose Vb [s2][h*64+d] -> Vt [b][h][d][s]
// ---------------------------------------------------------------------------
__global__ __launch_bounds__(256) void vtrans(
    const unsigned short* __restrict__ Vb, unsigned short* __restrict__ Vt)
{
    __shared__ unsigned short T[64][66];
    const int t = threadIdx.x;
    const int s0 = blockIdx.x * 64, h = blockIdx.y, b = blockIdx.z;

    {
        const int s_l = t >> 2, d0 = (t & 3) * 16;
        const unsigned short* src = Vb + (((size_t)(s0 + s_l) * 2 + b) << 10) + (h << 6) + d0;
        *(ushort8*)&T[s_l][d0]     = *(const ushort8*)src;
        *(ushort8*)&T[s_l][d0 + 8] = *(const ushort8*)(src + 8);
    }
    __syncthreads();
    {
        const int d_l = t >> 2, sc = (t & 3) * 16;
        ushort8 o0, o1;
        #pragma unroll
        for (int j = 0; j < 8; ++j) { o0[j] = T[sc + j][d_l]; o1[j] = T[sc + 8 + j][d_l]; }
        unsigned short* dst = Vt + (((size_t)((b << 4) + h) * 64 + d_l) << 11) + s0 + sc;
        *(ushort8*)dst       = o0;
        *(ushort8*)(dst + 8) = o1;
    }
}

// ---------------------------------------------------------------------------
// attn2: swapped-QK^T fused attention. 128 q/block, 4 waves x 32 q.
// Lane (fr,fg) after mfma(K,Q) holds S[q=fr][k = n*16+fg*4+r] (r consecutive!)
// -> attn written as dwordx4 from regs; P packed to LDS as b64 for PV.
// ---------------------------------------------------------------------------
__global__ __launch_bounds__(256) void attn2(
    const unsigned short* __restrict__ Qb, const unsigned short* __restrict__ Kb,
    const unsigned short* __restrict__ Vt, float* __restrict__ attn_out,
    unsigned short* __restrict__ Hb)
{
    __shared__ unsigned short Ks[128 * 64];      // 16 KB, swizzled 128B rows
    __shared__ unsigned short Pl[4 * 32 * 128];  // 32 KB, per-wave 32x128 bf16

    const int flat = blockIdx.x + (blockIdx.y << 4) + (blockIdx.z << 8);
    const int nf = (flat & 7) * 64 + (flat >> 3);
    const int qblk = nf & 15, h = (nf >> 4) & 15, b = nf >> 8;

    const int t = threadIdx.x, lane = t & 63, w = t >> 6;
    const int fr = lane & 15, fg = lane >> 4;
    const int fg4 = fg << 2, fg16 = fg << 4;
    const int qbase = qblk * 128 + w * 32;
    const float scale = 0.125f;

    bf16x8 qf[2][2];
    #pragma unroll
    for (int mi = 0; mi < 2; ++mi) {
        const int q = qbase + mi * 16 + fr;
        const unsigned short* qp = Qb + (((size_t)q * 2 + b) << 10) + (h << 6);
        qf[mi][0] = *(const bf16x8*)(qp + (fg << 3));
        qf[mi][1] = *(const bf16x8*)(qp + 32 + (fg << 3));
    }

    const char* Ksc = (const char*)Ks;
    char* Plc = (char*)&Pl[w * 4096];

    float lsum[2] = {0.f, 0.f};

    // ---------------- pass 1: row sums ----------------
    for (int kt = 0; kt < 16; ++kt) {
        __syncthreads();
        #pragma unroll
        for (int c = 0; c < 4; ++c) {
            const int rb = (w << 5) + (c << 3);
            const int row_l = rb + (lane >> 3);
            const unsigned short* src = Kb + (((size_t)((kt << 7) + row_l) * 2 + b) << 10) + (h << 6)
                                         + (((lane & 7) ^ (row_l & 7)) << 3);
            GLOAD_LDS16(src, &Ks[rb * 64]);
        }
        __syncthreads();

        f32x4 s_[2][8] = {};
        __builtin_amdgcn_s_setprio(1);
        #pragma unroll
        for (int n = 0; n < 8; ++n) {
            const int row = (n << 4) + fr;
            const int rx = (row & 7) << 4;
            #pragma unroll
            for (int kk = 0; kk < 2; ++kk) {
                bf16x8 kf = *(const bf16x8*)(Ksc + (row << 7) + (((kk << 6) | fg16) ^ rx));
                s_[0][n] = MFMA16(kf, qf[0][kk], s_[0][n]);
                s_[1][n] = MFMA16(kf, qf[1][kk], s_[1][n]);
            }
        }
        __builtin_amdgcn_s_setprio(0);
        #pragma unroll
        for (int mi = 0; mi < 2; ++mi) {
            float a = 0.f;
            #pragma unroll
            for (int n = 0; n < 8; ++n)
                #pragma unroll
                for (int r = 0; r < 4; ++r)
                    a += __expf(fminf(s_[mi][n][r] * scale, 60.f));
            lsum[mi] += a;
        }
    }

    float inv[2];
    #pragma unroll
    for (int mi = 0; mi < 2; ++mi) {
        float v = lsum[mi];
        v += __shfl_xor(v, 16);
        v += __shfl_xor(v, 32);
        inv[mi] = 1.f / v;
    }

    f32x4 oacc[2][4] = {};
    float* attnB = attn_out + ((size_t)((b << 4) + h) << 22);
    const size_t vhead = (size_t)((b << 4) + h) << 6;

    // ---------------- pass 2 ----------------
    for (int kt = 0; kt < 16; ++kt) {
        __syncthreads();
        #pragma unroll
        for (int c = 0; c < 4; ++c) {
            const int rb = (w << 5) + (c << 3);
            const int row_l = rb + (lane >> 3);
            const unsigned short* src = Kb + (((size_t)((kt << 7) + row_l) * 2 + b) << 10) + (h << 6)
                                         + (((lane & 7) ^ (row_l & 7)) << 3);
            GLOAD_LDS16(src, &Ks[rb * 64]);
        }
        __syncthreads();

        f32x4 s_[2][8] = {};
        __builtin_amdgcn_s_setprio(1);
        #pragma unroll
        for (int n = 0; n < 8; ++n) {
            const int row = (n << 4) + fr;
            const int rx = (row & 7) << 4;
            #pragma unroll
            for (int kk = 0; kk < 2; ++kk) {
                bf16x8 kf = *(const bf16x8*)(Ksc + (row << 7) + (((kk << 6) | fg16) ^ rx));
                s_[0][n] = MFMA16(kf, qf[0][kk], s_[0][n]);
                s_[1][n] = MFMA16(kf, qf[1][kk], s_[1][n]);
            }
        }
        __builtin_amdgcn_s_setprio(0);

        // p = exp*inv; dwordx4 attn store from regs; packed b64 -> Pl
        #pragma unroll
        for (int mi = 0; mi < 2; ++mi) {
            float* ab = attnB + ((size_t)(qbase + mi * 16 + fr) << 11) + (kt << 7) + fg4;
            const int row_l = mi * 16 + fr;
            const int rxl = (row_l & 7) << 4;
            #pragma unroll
            for (int n = 0; n < 8; ++n) {
                f32x4 p;
                #pragma unroll
                for (int r = 0; r < 4; ++r)
                    p[r] = __expf(fminf(s_[mi][n][r] * scale, 60.f)) * inv[mi];
                *(f32x4*)(ab + (n << 4)) = p;
                unsigned int lo = pack_bf16_pair(p[0], p[1]);
                unsigned int hi = pack_bf16_pair(p[2], p[3]);
                uint2 pk = {lo, hi};
                *(uint2*)(Plc + (row_l << 8) + (((n << 5) | (fg << 3)) ^ rxl)) = pk;
            }
        }
        asm volatile("s_waitcnt lgkmcnt(0)" ::: "memory");
        __builtin_amdgcn_sched_barrier(0);

        // PV: oacc += P(32x128) @ V(128x64)
        __builtin_amdgcn_s_setprio(1);
        #pragma unroll
        for (int kk2 = 0; kk2 < 4; ++kk2) {
            const int cb = ((kk2 << 6) | fg16) ^ ((fr & 7) << 4);
            bf16x8 pa0 = *(const bf16x8*)(Plc + (fr << 8) + cb);
            bf16x8 pa1 = *(const bf16x8*)(Plc + ((16 + fr) << 8) + cb);
            #pragma unroll
            for (int n2 = 0; n2 < 4; ++n2) {
                bf16x8 vf = *(const bf16x8*)(Vt + ((vhead + (n2 << 4) + fr) << 11)
                                             + (kt << 7) + (kk2 << 5) + (fg << 3));
                oacc[0][n2] = MFMA16(pa0, vf, oacc[0][n2]);
                oacc[1][n2] = MFMA16(pa1, vf, oacc[1][n2]);
            }
        }
        __builtin_amdgcn_s_setprio(0);
    }

    #pragma unroll
    for (int mi = 0; mi < 2; ++mi)
        #pragma unroll
        for (int n2 = 0; n2 < 4; ++n2)
            #pragma unroll
            for (int r = 0; r < 4; ++r) {
                const int q = qbase + (mi << 4) + fg4 + r;
                *(__bf16*)&Hb[(((size_t)q * 2 + b) << 10) + (h << 6) + (n2 << 4) + fr] =
                    (__bf16)oacc[mi][n2][r];
            }
}

// ---------------------------------------------------------------------------
// out_proj: out = H @ Wob^T + bo (fp32), both operands bf16 via gload_lds.
// ---------------------------------------------------------------------------
__global__ __launch_bounds__(256) void out_proj(
    const unsigned short* __restrict__ Hb, const unsigned short* __restrict__ Wob,
    const float* __restrict__ bo, float* __restrict__ out)
{
    __shared__ unsigned short As[128 * 64];
    __shared__ unsigned short Bs[128 * 64];

    const int t = threadIdx.x, lane = t & 63, w = t >> 6;
    const int wm = w >> 1, wn = w & 1;
    const int bm = blockIdx.x * 128, bn = blockIdx.y * 128;
    const int fr = lane & 15, fg = lane >> 4;

    f32x4 acc[4][4] = {};
    const char* Ac = (const char*)As;
    const char* Bc = (const char*)Bs;

    for (int k0 = 0; k0 < HID; k0 += 64) {
        __syncthreads();
        GEMM_STAGE(As, Hb + (size_t)bm * HID)
        GEMM_STAGE(Bs, Wob + (size_t)bn * HID)
        __syncthreads();

        #pragma unroll
        for (int kk = 0; kk < 2; ++kk) {
            bf16x8 a_h[4], b_h[4];
            #pragma unroll
            for (int m = 0; m < 4; ++m) {
                const int row = wm * 64 + m * 16 + fr;
                a_h[m] = *(const bf16x8*)(Ac + (row << 7) + (((kk << 6) | (fg << 4)) ^ ((row & 7) << 4)));
            }
            #pragma unroll
            for (int n = 0; n < 4; ++n) {
                const int row = wn * 64 + n * 16 + fr;
                b_h[n] = *(const bf16x8*)(Bc + (row << 7) + (((kk << 6) | (fg << 4)) ^ ((row & 7) << 4)));
            }
            __builtin_amdgcn_s_setprio(1);
            #pragma unroll
            for (int m = 0; m < 4; ++m)
                #pragma unroll
                for (int n = 0; n < 4; ++n)
                    acc[m][n] = MFMA16(a_h[m], b_h[n], acc[m][n]);
            __builtin_amdgcn_s_setprio(0);
        }
    }

    #pragma unroll
    for (int n = 0; n < 4; ++n) {
        const int gc = bn + wn * 64 + n * 16 + fr;
        const float bb = bo[gc];
        #pragma unroll
        for (int m = 0; m < 4; ++m)
            #pragma unroll
            for (int r = 0; r < 4; ++r) {
                const int gr = bm + wm * 64 + m * 16 + fg * 4 + r;
                out[(size_t)gr * HID + gc] = acc[m][n][r] + bb;
            }
    }
}

// ---------------------------------------------------------------------------
extern "C" void kernel_launch(void* const* d_in, const int* in_sizes, int n_in,
                              void* d_out, int out_size, void* d_ws, size_t ws_size,
                              hipStream_t stream)
{
    (void)in_sizes; (void)n_in; (void)out_size;

    const float* query = (const float*)d_in[0];
    const float* key   = (const float*)d_in[1];
    const float* value = (const float*)d_in[2];
    const float* bq    = (const float*)d_in[4];
    const float* bk    = (const float*)d_in[6];
    const float* bv    = (const float*)d_in[8];
    const float* Wo    = (const float*)d_in[9];
    const float* bo    = (const float*)d_in[10];

    float* out0 = (float*)d_out;
    float* attn = out0 + (size_t)MROWS * HID;

    if (ws_size < (size_t)32 * 1024 * 1024) return;
    const size_t nbuf = (size_t)MROWS * HID;            // 4M bf16 = 8MB
    unsigned short* Qb = (unsigned short*)d_ws;         // [0, 8MB)
    unsigned short* Kb = Qb + nbuf;                     // [8, 16MB)
    unsigned short* Vb = Kb + nbuf;                     // [16, 24MB) -> Hb after vtrans
    unsigned short* Vt = Vb + nbuf;                     // [24, 32MB)
    unsigned short* Hb = Vb;
    unsigned short* Wob = Qb;                           // Qb dead after attn2

    unsigned short* Sc = (unsigned short*)attn;         // scratch inside attn area (30MB)

    conv6<<<dim3(2048, 6), 256, 0, stream>>>(query, key, value,
                                             (const float*)d_in[3], (const float*)d_in[5],
                                             (const float*)d_in[7], Sc);
    qkv_gemm<<<dim3(32, 8, 3), 256, 0, stream>>>(Sc, bq, bk, bv, Qb, Kb, Vb);
    vtrans<<<dim3(32, NHEAD, NBATCH), 256, 0, stream>>>(Vb, Vt);
    attn2<<<dim3(16, NHEAD, NBATCH), 256, 0, stream>>>(Qb, Kb, Vt, attn, Hb);
    wconv<<<dim3(512), 256, 0, stream>>>(Wo, Wob);
    out_proj<<<dim3(32, 8), 256, 0, stream>>>(Hb, Wob, bo, out0);
}

// Round 4
// 318.931 us; speedup vs baseline: 1.4004x; 1.0242x over previous
//
#include <hip/hip_runtime.h>
#include <hip/hip_bf16.h>
#include <cstdint>
#include <cstddef>

#define SEQLEN 2048
#define NBATCH 2
#define NHEAD  16
#define HDIM   64
#define HID    1024
#define MROWS  4096   // row r = s*2 + b

typedef __bf16 bf16x8 __attribute__((ext_vector_type(8)));
typedef float f32x4 __attribute__((ext_vector_type(4)));
typedef unsigned short ushort8 __attribute__((ext_vector_type(8)));

#define MFMA16(a, b, c) __builtin_amdgcn_mfma_f32_16x16x32_bf16((a), (b), (c), 0, 0, 0)

#define GLOAD_LDS16(g, l)                                                        \
    __builtin_amdgcn_global_load_lds(                                            \
        (const __attribute__((address_space(1))) void*)(g),                      \
        (__attribute__((address_space(3))) void*)(l), 16, 0, 0)

#define SBAR() __builtin_amdgcn_s_barrier()
#define SCHED_FENCE() __builtin_amdgcn_sched_barrier(0)
#define WAIT_VMCNT(n) asm volatile("s_waitcnt vmcnt(" #n ")" ::: "memory")

static __device__ __forceinline__ unsigned int pack_bf16_pair(float lo, float hi) {
    unsigned short a = __builtin_bit_cast(unsigned short, (__bf16)lo);
    unsigned short b = __builtin_bit_cast(unsigned short, (__bf16)hi);
    return ((unsigned int)b << 16) | a;
}

// ---------------------------------------------------------------------------
// conv6: fp32 -> bf16 for {query,key,value,Wq,Wk,Wv} into scratch (attn area)
// ---------------------------------------------------------------------------
__global__ __launch_bounds__(256) void conv6(
    const float* __restrict__ s0, const float* __restrict__ s1, const float* __restrict__ s2,
    const float* __restrict__ s3, const float* __restrict__ s4, const float* __restrict__ s5,
    unsigned short* __restrict__ Sc)
{
    const int y = blockIdx.y;
    const float* src = (y == 0) ? s0 : (y == 1) ? s1 : (y == 2) ? s2
                     : (y == 3) ? s3 : (y == 4) ? s4 : s5;
    const size_t M1 = 1u << 20;
    unsigned short* dst = (y < 3) ? (Sc + (size_t)y * 4 * M1) : (Sc + 12 * M1 + (size_t)(y - 3) * M1);
    const size_t n = (y < 3) ? 4 * M1 : M1;

    const size_t i = ((size_t)blockIdx.x * 256 + threadIdx.x) * 8;
    if (i >= n) return;
    float4 f0 = *(const float4*)(src + i);
    float4 f1 = *(const float4*)(src + i + 4);
    ushort8 o;
    o[0] = __builtin_bit_cast(unsigned short, (__bf16)f0.x);
    o[1] = __builtin_bit_cast(unsigned short, (__bf16)f0.y);
    o[2] = __builtin_bit_cast(unsigned short, (__bf16)f0.z);
    o[3] = __builtin_bit_cast(unsigned short, (__bf16)f0.w);
    o[4] = __builtin_bit_cast(unsigned short, (__bf16)f1.x);
    o[5] = __builtin_bit_cast(unsigned short, (__bf16)f1.y);
    o[6] = __builtin_bit_cast(unsigned short, (__bf16)f1.z);
    o[7] = __builtin_bit_cast(unsigned short, (__bf16)f1.w);
    *(ushort8*)(dst + i) = o;
}

__global__ __launch_bounds__(256) void wconv(
    const float* __restrict__ Wo, unsigned short* __restrict__ Wob)
{
    const size_t i = ((size_t)blockIdx.x * 256 + threadIdx.x) * 8;
    float4 f0 = *(const float4*)(Wo + i);
    float4 f1 = *(const float4*)(Wo + i + 4);
    ushort8 o;
    o[0] = __builtin_bit_cast(unsigned short, (__bf16)f0.x);
    o[1] = __builtin_bit_cast(unsigned short, (__bf16)f0.y);
    o[2] = __builtin_bit_cast(unsigned short, (__bf16)f0.z);
    o[3] = __builtin_bit_cast(unsigned short, (__bf16)f0.w);
    o[4] = __builtin_bit_cast(unsigned short, (__bf16)f1.x);
    o[5] = __builtin_bit_cast(unsigned short, (__bf16)f1.y);
    o[6] = __builtin_bit_cast(unsigned short, (__bf16)f1.z);
    o[7] = __builtin_bit_cast(unsigned short, (__bf16)f1.w);
    *(ushort8*)(Wob + i) = o;
}

// ---------------------------------------------------------------------------
// Double-buffered bf16 GEMM (BK=32): per-iter {sbar; stage(next); vmcnt(8);
// sbar; frag reads + 16 MFMA}. LDS 32 KB. Row swizzle: slot ^= (row>>1)&3.
// ---------------------------------------------------------------------------
#define GSTAGE32(DSTARR, SRCP, k0v)                                              \
    _Pragma("unroll")                                                            \
    for (int c_ = 0; c_ < 2; ++c_) {                                             \
        const int row_ = (c_ << 6) + (threadIdx.x >> 2);                         \
        const unsigned short* gs_ = (SRCP) + (size_t)row_ * HID + (k0v)          \
            + ((((int)threadIdx.x & 3) ^ ((row_ >> 1) & 3)) << 3);               \
        GLOAD_LDS16(gs_, &(DSTARR)[((c_ << 6) + (((int)threadIdx.x >> 6) << 4)) * 32]); \
    }

#define GEMM_BODY(ApT, BpT)                                                      \
    GSTAGE32(As[0], ApT, 0);                                                     \
    GSTAGE32(Bs[0], BpT, 0);                                                     \
    for (int it = 0; it < 32; ++it) {                                            \
        SBAR();                                                                  \
        const int k1 = ((it + 1) & 31) << 5;                                     \
        GSTAGE32(As[(it + 1) & 1], ApT, k1);                                     \
        GSTAGE32(Bs[(it + 1) & 1], BpT, k1);                                     \
        WAIT_VMCNT(8);                                                           \
        SBAR();                                                                  \
        SCHED_FENCE();                                                           \
        const char* Ac = (const char*)As[it & 1];                                \
        const char* Bc = (const char*)Bs[it & 1];                                \
        bf16x8 a_h[4], b_h[4];                                                   \
        _Pragma("unroll")                                                        \
        for (int m = 0; m < 4; ++m) {                                            \
            const int row = wm * 64 + m * 16 + fr;                               \
            a_h[m] = *(const bf16x8*)(Ac + (row << 6) + ((fg ^ ((row >> 1) & 3)) << 4)); \
        }                                                                        \
        _Pragma("unroll")                                                        \
        for (int n = 0; n < 4; ++n) {                                            \
            const int row = wn * 64 + n * 16 + fr;                               \
            b_h[n] = *(const bf16x8*)(Bc + (row << 6) + ((fg ^ ((row >> 1) & 3)) << 4)); \
        }                                                                        \
        __builtin_amdgcn_s_setprio(1);                                           \
        _Pragma("unroll")                                                        \
        for (int m = 0; m < 4; ++m)                                              \
            _Pragma("unroll")                                                    \
            for (int n = 0; n < 4; ++n)                                          \
                acc[m][n] = MFMA16(a_h[m], b_h[n], acc[m][n]);                   \
        __builtin_amdgcn_s_setprio(0);                                           \
    }

__global__ __launch_bounds__(256) void qkv_gemm(
    const unsigned short* __restrict__ Sc,
    const float* __restrict__ bq, const float* __restrict__ bk, const float* __restrict__ bv,
    unsigned short* __restrict__ Qb, unsigned short* __restrict__ Kb, unsigned short* __restrict__ Vb)
{
    const int z = blockIdx.z;
    const size_t M1 = 1u << 20;
    const unsigned short* A = Sc + (size_t)z * 4 * M1;
    const unsigned short* B = Sc + 12 * M1 + (size_t)z * M1;
    const float* bias = (z == 0) ? bq : (z == 1) ? bk : bv;
    unsigned short* dst = (z == 0) ? Qb : (z == 1) ? Kb : Vb;

    __shared__ unsigned short As[2][128 * 32];
    __shared__ unsigned short Bs[2][128 * 32];

    const int t = threadIdx.x, lane = t & 63, w = t >> 6;
    const int wm = w >> 1, wn = w & 1;
    const int bm = blockIdx.x * 128, bn = blockIdx.y * 128;
    const int fr = lane & 15, fg = lane >> 4;

    const unsigned short* Ap = A + (size_t)bm * HID;
    const unsigned short* Bp = B + (size_t)bn * HID;

    f32x4 acc[4][4] = {};
    GEMM_BODY(Ap, Bp)

    #pragma unroll
    for (int n = 0; n < 4; ++n) {
        const int gc = bn + wn * 64 + n * 16 + fr;
        const float bb = bias[gc];
        #pragma unroll
        for (int m = 0; m < 4; ++m)
            #pragma unroll
            for (int r = 0; r < 4; ++r) {
                const int gr = bm + wm * 64 + m * 16 + fg * 4 + r;
                *(__bf16*)&dst[(size_t)gr * HID + gc] = (__bf16)(acc[m][n][r] + bb);
            }
    }
}

// ---------------------------------------------------------------------------
// vtrans: LDS-tiled transpose Vb [s2][h*64+d] -> Vt [b][h][d][s]
// ---------------------------------------------------------------------------
__global__ __launch_bounds__(256) void vtrans(
    const unsigned short* __restrict__ Vb, unsigned short* __restrict__ Vt)
{
    __shared__ unsigned short T[64][66];
    const int t = threadIdx.x;
    const int s0 = blockIdx.x * 64, h = blockIdx.y, b = blockIdx.z;

    {
        const int s_l = t >> 2, d0 = (t & 3) * 16;
        const unsigned short* src = Vb + (((size_t)(s0 + s_l) * 2 + b) << 10) + (h << 6) + d0;
        *(ushort8*)&T[s_l][d0]     = *(const ushort8*)src;
        *(ushort8*)&T[s_l][d0 + 8] = *(const ushort8*)(src + 8);
    }
    __syncthreads();
    {
        const int d_l = t >> 2, sc = (t & 3) * 16;
        ushort8 o0, o1;
        #pragma unroll
        for (int j = 0; j < 8; ++j) { o0[j] = T[sc + j][d_l]; o1[j] = T[sc + 8 + j][d_l]; }
        unsigned short* dst = Vt + (((size_t)((b << 4) + h) * 64 + d_l) << 11) + s0 + sc;
        *(ushort8*)dst       = o0;
        *(ushort8*)(dst + 8) = o1;
    }
}

// ---------------------------------------------------------------------------
// attn2: swapped-QK^T fused attention, double-buffered K staging with counted
// vmcnt. Lane (fr,fg): q=fr, k=16n+fg*4+r. LDS 48 KB (3 blocks/CU).
// ---------------------------------------------------------------------------
#define STAGE_K(ktv, bufsel)                                                     \
    {                                                                            \
        const int kti_ = (ktv) & 15;                                             \
        _Pragma("unroll")                                                        \
        for (int c_ = 0; c_ < 4; ++c_) {                                         \
            const int rb_ = (w << 5) + (c_ << 3);                                \
            const int rl_ = rb_ + (lane >> 3);                                   \
            const unsigned short* ks_ = Kb + (((size_t)((kti_ << 7) + rl_) * 2 + b) << 10) \
                + (h << 6) + (((lane & 7) ^ (rl_ & 7)) << 3);                    \
            GLOAD_LDS16(ks_, &Ks[bufsel][rb_ * 64]);                             \
        }                                                                        \
    }

__global__ __launch_bounds__(256) void attn2(
    const unsigned short* __restrict__ Qb, const unsigned short* __restrict__ Kb,
    const unsigned short* __restrict__ Vt, float* __restrict__ attn_out,
    unsigned short* __restrict__ Hb)
{
    __shared__ unsigned short Ks[2][128 * 64];   // 32 KB double-buffered K
    __shared__ unsigned short Pl[4][16 * 128];   // 16 KB, per-wave 16x128 bf16

    const int flat = blockIdx.x + (blockIdx.y << 4) + (blockIdx.z << 8);
    const int nf = (flat & 7) * 64 + (flat >> 3);
    const int qblk = nf & 15, h = (nf >> 4) & 15, b = nf >> 8;

    const int t = threadIdx.x, lane = t & 63, w = t >> 6;
    const int fr = lane & 15, fg = lane >> 4;
    const int fg4 = fg << 2, fg16 = fg << 4;
    const int qbase = qblk * 128 + w * 32;
    const float c_exp = 0.18033688011112042f;    // log2(e)/8

    bf16x8 qf[2][2];
    #pragma unroll
    for (int mi = 0; mi < 2; ++mi) {
        const int q = qbase + mi * 16 + fr;
        const unsigned short* qp = Qb + (((size_t)q * 2 + b) << 10) + (h << 6);
        qf[mi][0] = *(const bf16x8*)(qp + (fg << 3));
        qf[mi][1] = *(const bf16x8*)(qp + 32 + (fg << 3));
    }

    char* Plc = (char*)&Pl[w][0];
    float lsum[2] = {0.f, 0.f};

    // ---------------- pass 1: row sums ----------------
    STAGE_K(0, 0);
    for (int kt = 0; kt < 16; ++kt) {
        SBAR();
        STAGE_K(kt + 1, (kt + 1) & 1);
        WAIT_VMCNT(4);
        SBAR();
        SCHED_FENCE();

        const char* Kc = (const char*)Ks[kt & 1];
        f32x4 s_[2][8] = {};
        __builtin_amdgcn_s_setprio(1);
        #pragma unroll
        for (int n = 0; n < 8; ++n) {
            const int row = (n << 4) + fr;
            const int rx = (row & 7) << 4;
            #pragma unroll
            for (int kk = 0; kk < 2; ++kk) {
                bf16x8 kf = *(const bf16x8*)(Kc + (row << 7) + (((kk << 6) | fg16) ^ rx));
                s_[0][n] = MFMA16(kf, qf[0][kk], s_[0][n]);
                s_[1][n] = MFMA16(kf, qf[1][kk], s_[1][n]);
            }
        }
        __builtin_amdgcn_s_setprio(0);

        #pragma unroll
        for (int mi = 0; mi < 2; ++mi) {
            float a = 0.f;
            #pragma unroll
            for (int n = 0; n < 8; ++n)
                #pragma unroll
                for (int r = 0; r < 4; ++r)
                    a += exp2f(s_[mi][n][r] * c_exp);
            lsum[mi] += a;
        }
    }

    float li[2];
    #pragma unroll
    for (int mi = 0; mi < 2; ++mi) {
        float v = lsum[mi];
        v += __shfl_xor(v, 16);
        v += __shfl_xor(v, 32);
        li[mi] = -__log2f(v);                    // fold 1/sum into exponent
    }

    f32x4 oacc[2][4] = {};
    float* attnB = attn_out + ((size_t)((b << 4) + h) << 22);
    const size_t vhead = (size_t)((b << 4) + h) << 6;

    // ---------------- pass 2 ----------------
    // pass 1's final STAGE_K already put kt=0 into Ks[0].
    for (int kt = 0; kt < 16; ++kt) {
        SBAR();
        STAGE_K(kt + 1, (kt + 1) & 1);
        WAIT_VMCNT(4);
        SBAR();
        SCHED_FENCE();

        const char* Kc = (const char*)Ks[kt & 1];
        f32x4 s_[2][8] = {};
        __builtin_amdgcn_s_setprio(1);
        #pragma unroll
        for (int n = 0; n < 8; ++n) {
            const int row = (n << 4) + fr;
            const int rx = (row & 7) << 4;
            #pragma unroll
            for (int kk = 0; kk < 2; ++kk) {
                bf16x8 kf = *(const bf16x8*)(Kc + (row << 7) + (((kk << 6) | fg16) ^ rx));
                s_[0][n] = MFMA16(kf, qf[0][kk], s_[0][n]);
                s_[1][n] = MFMA16(kf, qf[1][kk], s_[1][n]);
            }
        }
        __builtin_amdgcn_s_setprio(0);

        const int rxl = (fr & 7) << 4;
        #pragma unroll
        for (int mi = 0; mi < 2; ++mi) {
            // p = 2^(s*c + log2(inv)); NT store to attn; packed b64 -> Pl
            float* ab = attnB + ((size_t)(qbase + (mi << 4) + fr) << 11) + (kt << 7) + fg4;
            #pragma unroll
            for (int n = 0; n < 8; ++n) {
                f32x4 p;
                #pragma unroll
                for (int r = 0; r < 4; ++r)
                    p[r] = exp2f(__builtin_fmaf(s_[mi][n][r], c_exp, li[mi]));
                __builtin_nontemporal_store(p, (f32x4*)(ab + (n << 4)));
                uint2 pk;
                pk.x = pack_bf16_pair(p[0], p[1]);
                pk.y = pack_bf16_pair(p[2], p[3]);
                *(uint2*)(Plc + (fr << 8) + (((n << 5) | (fg << 3)) ^ rxl)) = pk;
            }
            asm volatile("s_waitcnt lgkmcnt(0)" ::: "memory");
            SCHED_FENCE();

            // PV (this mi): oacc[mi] += P(16x128) @ V(128x64)
            __builtin_amdgcn_s_setprio(1);
            #pragma unroll
            for (int kk2 = 0; kk2 < 4; ++kk2) {
                bf16x8 pa = *(const bf16x8*)(Plc + (fr << 8) + (((kk2 << 6) | fg16) ^ rxl));
                #pragma unroll
                for (int n2 = 0; n2 < 4; ++n2) {
                    bf16x8 vf = *(const bf16x8*)(Vt + ((vhead + (n2 << 4) + fr) << 11)
                                                 + (kt << 7) + (kk2 << 5) + (fg << 3));
                    oacc[mi][n2] = MFMA16(pa, vf, oacc[mi][n2]);
                }
            }
            __builtin_amdgcn_s_setprio(0);
        }
    }

    #pragma unroll
    for (int mi = 0; mi < 2; ++mi)
        #pragma unroll
        for (int n2 = 0; n2 < 4; ++n2)
            #pragma unroll
            for (int r = 0; r < 4; ++r) {
                const int q = qbase + (mi << 4) + fg4 + r;
                *(__bf16*)&Hb[(((size_t)q * 2 + b) << 10) + (h << 6) + (n2 << 4) + fr] =
                    (__bf16)oacc[mi][n2][r];
            }
}

// ---------------------------------------------------------------------------
// out_proj: out = H @ Wob^T + bo (fp32), double-buffered BK=32.
// ---------------------------------------------------------------------------
__global__ __launch_bounds__(256) void out_proj(
    const unsigned short* __restrict__ Hb, const unsigned short* __restrict__ Wob,
    const float* __restrict__ bo, float* __restrict__ out)
{
    __shared__ unsigned short As[2][128 * 32];
    __shared__ unsigned short Bs[2][128 * 32];

    const int t = threadIdx.x, lane = t & 63, w = t >> 6;
    const int wm = w >> 1, wn = w & 1;
    const int bm = blockIdx.x * 128, bn = blockIdx.y * 128;
    const int fr = lane & 15, fg = lane >> 4;

    const unsigned short* Ap = Hb + (size_t)bm * HID;
    const unsigned short* Bp = Wob + (size_t)bn * HID;

    f32x4 acc[4][4] = {};
    GEMM_BODY(Ap, Bp)

    #pragma unroll
    for (int n = 0; n < 4; ++n) {
        const int gc = bn + wn * 64 + n * 16 + fr;
        const float bb = bo[gc];
        #pragma unroll
        for (int m = 0; m < 4; ++m)
            #pragma unroll
            for (int r = 0; r < 4; ++r) {
                const int gr = bm + wm * 64 + m * 16 + fg * 4 + r;
                out[(size_t)gr * HID + gc] = acc[m][n][r] + bb;
            }
    }
}

// ---------------------------------------------------------------------------
extern "C" void kernel_launch(void* const* d_in, const int* in_sizes, int n_in,
                              void* d_out, int out_size, void* d_ws, size_t ws_size,
                              hipStream_t stream)
{
    (void)in_sizes; (void)n_in; (void)out_size;

    const float* query = (const float*)d_in[0];
    const float* key   = (const float*)d_in[1];
    const float* value = (const float*)d_in[2];
    const float* bq    = (const float*)d_in[4];
    const float* bk    = (const float*)d_in[6];
    const float* bv    = (const float*)d_in[8];
    const float* Wo    = (const float*)d_in[9];
    const float* bo    = (const float*)d_in[10];

    float* out0 = (float*)d_out;
    float* attn = out0 + (size_t)MROWS * HID;

    if (ws_size < (size_t)32 * 1024 * 1024) return;
    const size_t nbuf = (size_t)MROWS * HID;            // 4M bf16 = 8MB
    unsigned short* Qb = (unsigned short*)d_ws;         // [0, 8MB)
    unsigned short* Kb = Qb + nbuf;                     // [8, 16MB)
    unsigned short* Vb = Kb + nbuf;                     // [16, 24MB) -> Hb after vtrans
    unsigned short* Vt = Vb + nbuf;                     // [24, 32MB)
    unsigned short* Hb = Vb;
    unsigned short* Wob = Qb;                           // Qb dead after attn2

    unsigned short* Sc = (unsigned short*)attn;         // scratch inside attn area (30MB)

    conv6<<<dim3(2048, 6), 256, 0, stream>>>(query, key, value,
                                             (const float*)d_in[3], (const float*)d_in[5],
                                             (const float*)d_in[7], Sc);
    qkv_gemm<<<dim3(32, 8, 3), 256, 0, stream>>>(Sc, bq, bk, bv, Qb, Kb, Vb);
    vtrans<<<dim3(32, NHEAD, NBATCH), 256, 0, stream>>>(Vb, Vt);
    attn2<<<dim3(16, NHEAD, NBATCH), 256, 0, stream>>>(Qb, Kb, Vt, attn, Hb);
    wconv<<<dim3(512), 256, 0, stream>>>(Wo, Wob);
    out_proj<<<dim3(32, 8), 256, 0, stream>>>(Hb, Wob, bo, out0);
}